// Round 1
// baseline (318.848 us; speedup 1.0000x reference)
//
#include <hip/hip_runtime.h>
#include <math.h>

#define ATTRI 6
#define SQE   14
#define HWPX  16384            // 128*128
#define NB    8
#define S_C   HWPX             // channel stride in Pred
#define S_S   (4 * HWPX)       // sqe stride
#define S_A   (SQE * 4 * HWPX) // attr stride = 917504
#define S_N   (ATTRI * SQE * 4 * HWPX) // batch stride = 5505024
#define NPRED (NB * S_N)       // 44040192
#define NOUT  (NB * 3 * HWPX)  // 393216 composite elements

// ws layout (bytes)
#define WS_MM     0                     // 4 uints: minKey,maxKey,minKey2,maxKey2
#define WS_COUNTS 16                    // int[8*14*9] = 1008 ints
#define WS_LAW    4096                  // float[NOUT]
#define WS_WSUM   (4096 + NOUT * 4)     // float[NOUT]
#define WS_PART   (WS_WSUM + NOUT * 4)  // float[768]

// monotone float<->uint key (unsigned compare == float compare)
__device__ __forceinline__ unsigned fkey(float f) {
    unsigned u = __float_as_uint(f);
    return (u & 0x80000000u) ? ~u : (u | 0x80000000u);
}
__device__ __forceinline__ float fdec(unsigned k) {
    unsigned u = (k & 0x80000000u) ? (k & 0x7FFFFFFFu) : ~k;
    return __uint_as_float(u);
}
__device__ __forceinline__ float sigm(float x) { return 1.0f / (1.0f + expf(-x)); }

__global__ void k_init(unsigned* mm, int* counts) {
    int t = threadIdx.x;
    if (t == 0) { mm[0] = 0xFF800000u; mm[2] = 0xFF800000u; } // key(+inf) for min
    if (t == 1) { mm[1] = 0x007FFFFFu; mm[3] = 0x007FFFFFu; } // key(-inf) for max
    for (int i = t; i < NB * SQE * 9; i += blockDim.x) counts[i] = 0;
}

// Pass 1: global min/max of Pred (176 MB read)
__global__ __launch_bounds__(256) void k_minmax(const float4* __restrict__ p, unsigned* mm) {
    float lmin = INFINITY, lmax = -INFINITY;
    int stride = gridDim.x * blockDim.x;
    for (int i = blockIdx.x * blockDim.x + threadIdx.x; i < NPRED / 4; i += stride) {
        float4 v = p[i];
        lmin = fminf(fminf(lmin, fminf(v.x, v.y)), fminf(v.z, v.w));
        lmax = fmaxf(fmaxf(lmax, fmaxf(v.x, v.y)), fmaxf(v.z, v.w));
    }
#pragma unroll
    for (int o = 32; o; o >>= 1) {
        lmin = fminf(lmin, __shfl_down(lmin, o));
        lmax = fmaxf(lmax, __shfl_down(lmax, o));
    }
    __shared__ float smin[4], smax[4];
    int wid = threadIdx.x >> 6, lane = threadIdx.x & 63;
    if (lane == 0) { smin[wid] = lmin; smax[wid] = lmax; }
    __syncthreads();
    if (threadIdx.x == 0) {
        float bmin = fminf(fminf(smin[0], smin[1]), fminf(smin[2], smin[3]));
        float bmax = fmaxf(fmaxf(smax[0], smax[1]), fmaxf(smax[2], smax[3]));
        atomicMin(&mm[0], fkey(bmin));
        atomicMax(&mm[1], fkey(bmax));
    }
}

// Pass 2a (blocks [0,896)): color-threshold counts on attr 0
// Pass 2b (blocks [896,2432)): LAW = sum_s norm(attr2)+norm(attr3)+norm(attr5), ch 0..2
__global__ __launch_bounds__(256) void k_counts_law(const float* __restrict__ pred,
                                                    const unsigned* __restrict__ mm,
                                                    int* counts, float* __restrict__ law) {
    float mn = fdec(mm[0]);
    float d  = fdec(mm[1]) - mn;
    int b = blockIdx.x;
    if (b < 896) {
        int pair = b >> 3, slice = b & 7;
        int n = pair / SQE, s = pair % SQE;
        const float* base = pred + (size_t)n * S_N + (size_t)s * S_S; // attr 0
        int cnt[9];
#pragma unroll
        for (int j = 0; j < 9; j++) cnt[j] = 0;
        for (int k = 0; k < 8; k++) {
            int p = slice * 2048 + k * 256 + threadIdx.x;
            float a = (base[3 * S_C + p] - mn) / d;
            bool av = a > 0.8f;
#pragma unroll
            for (int ch = 0; ch < 3; ch++) {
                float g = (base[ch * S_C + p] - mn) / d;
                cnt[ch * 3 + 0] += (g > 0.0f && g < 0.2f && av) ? 1 : 0;
                cnt[ch * 3 + 1] += (g > 0.4f && g < 0.6f) ? 1 : 0;
                cnt[ch * 3 + 2] += (g > 0.8f) ? 1 : 0;
            }
        }
#pragma unroll
        for (int o = 32; o; o >>= 1) {
#pragma unroll
            for (int j = 0; j < 9; j++) cnt[j] += __shfl_down(cnt[j], o);
        }
        __shared__ int sc[4][9];
        int wid = threadIdx.x >> 6, lane = threadIdx.x & 63;
        if (lane == 0) {
#pragma unroll
            for (int j = 0; j < 9; j++) sc[wid][j] = cnt[j];
        }
        __syncthreads();
        if (threadIdx.x < 9) {
            int tot = sc[0][threadIdx.x] + sc[1][threadIdx.x] + sc[2][threadIdx.x] + sc[3][threadIdx.x];
            atomicAdd(&counts[(n * SQE + s) * 9 + threadIdx.x], tot);
        }
    } else {
        int idx = (b - 896) * 256 + threadIdx.x;   // 0..NOUT-1
        int hw = idx & (HWPX - 1);
        int nc = idx >> 14;
        int n = nc / 3, c = nc - 3 * (nc / 3);
        const float* pn = pred + (size_t)n * S_N + (size_t)c * S_C + hw;
        float sL = 0.f, sA = 0.f, sW = 0.f;
        for (int s = 0; s < SQE; s++) {
            size_t o = (size_t)s * S_S;
            sL += (pn[2 * (size_t)S_A + o] - mn) / d;
            sA += (pn[3 * (size_t)S_A + o] - mn) / d;
            sW += (pn[5 * (size_t)S_A + o] - mn) / d;
        }
        law[idx] = (sL + sA) + sW;
    }
}

// Pass 3: type_list (from counts) -> wsum(n,c,h,w) = sum_s region_soft*tl + its min/max
__global__ __launch_bounds__(256) void k_wsum(const float* __restrict__ pred,
                                              unsigned* mm, const int* __restrict__ counts,
                                              float* __restrict__ wsum) {
    __shared__ float tl[SQE][3];
    int tid = threadIdx.x;
    int n = blockIdx.x >> 6;   // 64 blocks per batch element
    if (tid < SQE * 3) {
        int s = tid / 3, ch = tid - 3 * (tid / 3);
        const int* cc = counts + (n * SQE + s) * 9 + ch * 3;
        int c0 = cc[0], c1 = cc[1], c2 = cc[2];
        tl[s][ch] = (c2 > c1 && c2 > c0) ? 1.0f : ((c1 > c0) ? 0.5f : 0.0f);
    }
    __syncthreads();
    if (tid < SQE) {
        int code = (int)(tl[tid][0] * 2.0f) * 9 + (int)(tl[tid][1] * 2.0f) * 3 + (int)(tl[tid][2] * 2.0f);
        if (!((0x0559E101u >> code) & 1u)) { tl[tid][0] = 0.f; tl[tid][1] = 0.f; tl[tid][2] = 0.f; }
    }
    __syncthreads();

    float mn = fdec(mm[0]);
    float d  = fdec(mm[1]) - mn;
    int idx = blockIdx.x * 256 + tid;
    int hw = idx & (HWPX - 1);
    const float* pr = pred + (size_t)n * S_N + 4 * (size_t)S_A + hw; // attr 4
    float a0 = 0.f, a1 = 0.f, a2 = 0.f;
    for (int s = 0; s < SQE; s++) {
        const float* ps = pr + (size_t)s * S_S;
        float g0 = (ps[0] - mn) / d;
        float g1 = (ps[S_C] - mn) / d;
        float g2 = (ps[2 * S_C] - mn) / d;
        float r = sigm((g0 - 0.9f) * 10.0f) * sigm((g1 - 0.9f) * 10.0f) * sigm((g2 - 0.9f) * 10.0f);
        a0 += r * tl[s][0];
        a1 += r * tl[s][1];
        a2 += r * tl[s][2];
    }
    wsum[(n * 3 + 0) * HWPX + hw] = a0;
    wsum[(n * 3 + 1) * HWPX + hw] = a1;
    wsum[(n * 3 + 2) * HWPX + hw] = a2;

    float lmin = fminf(a0, fminf(a1, a2));
    float lmax = fmaxf(a0, fmaxf(a1, a2));
#pragma unroll
    for (int o = 32; o; o >>= 1) {
        lmin = fminf(lmin, __shfl_down(lmin, o));
        lmax = fmaxf(lmax, __shfl_down(lmax, o));
    }
    __shared__ float smin[4], smax[4];
    int wid = tid >> 6, lane = tid & 63;
    if (lane == 0) { smin[wid] = lmin; smax[wid] = lmax; }
    __syncthreads();
    if (tid == 0) {
        float bmin = fminf(fminf(smin[0], smin[1]), fminf(smin[2], smin[3]));
        float bmax = fmaxf(fmaxf(smax[0], smax[1]), fmaxf(smax[2], smax[3]));
        atomicMin(&mm[2], fkey(bmin));
        atomicMax(&mm[3], fkey(bmax));
    }
}

// Pass 4: per-block deterministic partial sums of squared error
__global__ __launch_bounds__(512) void k_loss(const float* __restrict__ gt,
                                              const unsigned* __restrict__ mm,
                                              const float* __restrict__ law,
                                              const float* __restrict__ wsum,
                                              float* __restrict__ part) {
    float mn2 = fdec(mm[2]);
    float d2  = fdec(mm[3]) - mn2;
    int idx = blockIdx.x * 512 + threadIdx.x;  // 768 blocks * 512 = NOUT
    int hw = idx & (HWPX - 1);
    int nc = idx >> 14;
    int n = nc / 3, c = nc - 3 * (nc / 3);
    float gtn = (gt[((size_t)(n * 4 + c)) * HWPX + hw] + 1.0f) * 0.5f;
    float rc = (wsum[idx] - mn2) / d2;
    float comp = rc + law[idx];
    comp = fminf(fmaxf(comp, 0.0f), 1.0f);
    float diff = comp - gtn;
    float se = diff * diff;

    __shared__ float sdata[512];
    sdata[threadIdx.x] = se;
    __syncthreads();
#pragma unroll
    for (int s = 256; s > 0; s >>= 1) {
        if (threadIdx.x < s) sdata[threadIdx.x] += sdata[threadIdx.x + s];
        __syncthreads();
    }
    if (threadIdx.x == 0) part[blockIdx.x] = sdata[0];
}

// Pass 5: final deterministic reduce -> loss
__global__ __launch_bounds__(256) void k_final(const float* __restrict__ part, float* __restrict__ out) {
    __shared__ float sdata[256];
    float v = part[threadIdx.x] + part[threadIdx.x + 256] + part[threadIdx.x + 512];
    sdata[threadIdx.x] = v;
    __syncthreads();
#pragma unroll
    for (int s = 128; s > 0; s >>= 1) {
        if (threadIdx.x < s) sdata[threadIdx.x] += sdata[threadIdx.x + s];
        __syncthreads();
    }
    if (threadIdx.x == 0) out[0] = sdata[0] / (float)NOUT;   // * IMG_WEIGHT (1.0)
}

extern "C" void kernel_launch(void* const* d_in, const int* in_sizes, int n_in,
                              void* d_out, int out_size, void* d_ws, size_t ws_size,
                              hipStream_t stream) {
    const float* GT   = (const float*)d_in[0];
    const float* Pred = (const float*)d_in[1];
    float* out = (float*)d_out;
    char* ws = (char*)d_ws;
    unsigned* mm = (unsigned*)(ws + WS_MM);
    int* counts  = (int*)(ws + WS_COUNTS);
    float* law   = (float*)(ws + WS_LAW);
    float* wsum  = (float*)(ws + WS_WSUM);
    float* part  = (float*)(ws + WS_PART);

    k_init<<<1, 256, 0, stream>>>(mm, counts);
    k_minmax<<<1536, 256, 0, stream>>>((const float4*)Pred, mm);
    k_counts_law<<<896 + NOUT / 256, 256, 0, stream>>>(Pred, mm, counts, law);
    k_wsum<<<NB * HWPX / 256, 256, 0, stream>>>(Pred, mm, counts, wsum);
    k_loss<<<NOUT / 512, 512, 0, stream>>>(GT, mm, law, wsum, part);
    k_final<<<1, 256, 0, stream>>>(part, out);
}

// Round 2
// 310.323 us; speedup vs baseline: 1.0275x; 1.0275x over previous
//
#include <hip/hip_runtime.h>
#include <math.h>

#define ATTRI 6
#define SQE   14
#define HWPX  16384            // 128*128
#define NB    8
#define S_C   HWPX             // channel stride in Pred (floats)
#define S_S   (4 * HWPX)       // sqe stride
#define S_A   (SQE * 4 * HWPX) // attr stride = 917504
#define S_N   (ATTRI * SQE * 4 * HWPX) // batch stride = 5505024
#define NPRED (NB * S_N)       // 44040192
#define NOUT  (NB * 3 * HWPX)  // 393216 composite elements

// ws layout (bytes); first 4096 bytes zeroed by hipMemsetAsync each call
#define WS_MM     0                      // 4 uints: ~minKey, maxKey, ~minKey2, maxKey2 (atomicMax, init 0)
#define WS_CTR    16                     // 1 uint: last-block counter
#define WS_COUNTS 32                     // int[8*14*9] = 1008 ints (ends at 4064)
#define WS_LAW    4096                   // float[NOUT] raw sums
#define WS_WSUM   (4096 + NOUT * 4)      // float[NOUT]
#define WS_PART   (WS_WSUM + NOUT * 4)   // float[768]

// monotone float<->uint key (unsigned compare == float compare); inputs here are never NaN
__device__ __forceinline__ unsigned fkey(float f) {
    unsigned u = __float_as_uint(f);
    return (u & 0x80000000u) ? ~u : (u | 0x80000000u);
}
__device__ __forceinline__ float fdec(unsigned k) {
    unsigned u = (k & 0x80000000u) ? (k & 0x7FFFFFFFu) : ~k;
    return __uint_as_float(u);
}
__device__ __forceinline__ float sigm(float x) { return 1.0f / (1.0f + expf(-x)); }

__device__ __forceinline__ void blk_minmax_atomic(float mnl, float mxl, unsigned* mm, int mmOff) {
#pragma unroll
    for (int o = 32; o; o >>= 1) {
        mnl = fminf(mnl, __shfl_down(mnl, o));
        mxl = fmaxf(mxl, __shfl_down(mxl, o));
    }
    __shared__ float smn[4], smx[4];
    int wid = threadIdx.x >> 6, lane = threadIdx.x & 63;
    if (lane == 0) { smn[wid] = mnl; smx[wid] = mxl; }
    __syncthreads();
    if (threadIdx.x == 0) {
        float bmn = fminf(fminf(smn[0], smn[1]), fminf(smn[2], smn[3]));
        float bmx = fmaxf(fmaxf(smx[0], smx[1]), fmaxf(smx[2], smx[3]));
        atomicMax(&mm[mmOff + 0], ~fkey(bmn));   // min tracked as max of complemented key
        atomicMax(&mm[mmOff + 1], fkey(bmx));
    }
}

// Pass 1: single full read of Pred (176 MB): global min/max + raw LAW sums.
// Section A (blocks [0,384)): the 42 used planes of attrs {2,3,5} ch0..2 -> sum + minmax.
// Section B (blocks [384,2064)): the remaining 210 planes per batch -> minmax only.
__global__ __launch_bounds__(256) void k_p1(const float* __restrict__ pred, unsigned* mm,
                                            float4* __restrict__ slaw) {
    float mnl = INFINITY, mxl = -INFINITY;
    int b = blockIdx.x, t = threadIdx.x;
    if (b < 384) {
        int idx = b * 256 + t;               // float4 index into [n][c][hw/4]
        int hw4 = idx & 4095;
        int nc = idx >> 12;                  // 0..23
        int n = nc / 3, c = nc - 3 * (nc / 3);
        const float4* p = (const float4*)(pred + (size_t)n * S_N + (size_t)c * S_C) + hw4;
        float4 s = make_float4(0.f, 0.f, 0.f, 0.f);
        const int attrs[3] = {2, 3, 5};
#pragma unroll
        for (int ai = 0; ai < 3; ai++) {
            const float4* pa = p + (size_t)attrs[ai] * (S_A / 4);
#pragma unroll
            for (int ss = 0; ss < SQE; ss++) {
                float4 v = pa[(size_t)ss * (S_S / 4)];
                s.x += v.x; s.y += v.y; s.z += v.z; s.w += v.w;
                mnl = fminf(mnl, fminf(fminf(v.x, v.y), fminf(v.z, v.w)));
                mxl = fmaxf(mxl, fmaxf(fmaxf(v.x, v.y), fmaxf(v.z, v.w)));
            }
        }
        slaw[idx] = s;
    } else {
        int bb = b - 384;
        int n = bb / 210, pi = bb - 210 * n;
        int plane;                            // plane = a*56 + s*4 + c, the 210 not in section A
        if (pi < 112)      plane = pi;                                // attrs 0,1 (all)
        else if (pi < 126) plane = 112 + (pi - 112) * 4 + 3;          // attr 2 ch3
        else if (pi < 140) plane = 168 + (pi - 126) * 4 + 3;          // attr 3 ch3
        else if (pi < 196) plane = 224 + (pi - 140);                  // attr 4 (all)
        else               plane = 280 + (pi - 196) * 4 + 3;          // attr 5 ch3
        const float4* p = (const float4*)(pred + (size_t)n * S_N + (size_t)plane * HWPX);
#pragma unroll 4
        for (int k = 0; k < 16; k++) {
            float4 v = p[k * 256 + t];
            mnl = fminf(mnl, fminf(fminf(v.x, v.y), fminf(v.z, v.w)));
            mxl = fmaxf(mxl, fmaxf(fmaxf(v.x, v.y), fmaxf(v.z, v.w)));
        }
    }
    blk_minmax_atomic(mnl, mxl, mm, 0);
}

// Pass 2: color-threshold counts on attr 0 (bit-exact (x-mn)/d predicates), float4 loads.
__global__ __launch_bounds__(256) void k_counts(const float* __restrict__ pred,
                                                const unsigned* __restrict__ mm,
                                                int* __restrict__ counts) {
    float mn = fdec(~mm[0]);
    float d  = fdec(mm[1]) - mn;
    int b = blockIdx.x;                   // 896 blocks
    int pair = b >> 3, slice = b & 7;
    int n = pair / SQE, s = pair - SQE * (pair / SQE);
    const float4* base = (const float4*)(pred + (size_t)n * S_N + (size_t)s * S_S);
    int cnt[9];
#pragma unroll
    for (int j = 0; j < 9; j++) cnt[j] = 0;
#pragma unroll
    for (int k = 0; k < 2; k++) {
        int p = slice * 512 + k * 256 + threadIdx.x;    // float4 index within plane
        float4 va = base[3 * 4096 + p];
        float4 v0 = base[p];
        float4 v1 = base[4096 + p];
        float4 v2 = base[2 * 4096 + p];
        const float ax[4] = {va.x, va.y, va.z, va.w};
        const float cx[3][4] = {{v0.x, v0.y, v0.z, v0.w},
                                {v1.x, v1.y, v1.z, v1.w},
                                {v2.x, v2.y, v2.z, v2.w}};
#pragma unroll
        for (int e = 0; e < 4; e++) {
            float a = (ax[e] - mn) / d;
            bool av = a > 0.8f;
#pragma unroll
            for (int ch = 0; ch < 3; ch++) {
                float g = (cx[ch][e] - mn) / d;
                cnt[ch * 3 + 0] += (g > 0.0f && g < 0.2f && av) ? 1 : 0;
                cnt[ch * 3 + 1] += (g > 0.4f && g < 0.6f) ? 1 : 0;
                cnt[ch * 3 + 2] += (g > 0.8f) ? 1 : 0;
            }
        }
    }
#pragma unroll
    for (int o = 32; o; o >>= 1) {
#pragma unroll
        for (int j = 0; j < 9; j++) cnt[j] += __shfl_down(cnt[j], o);
    }
    __shared__ int sc[4][9];
    int wid = threadIdx.x >> 6, lane = threadIdx.x & 63;
    if (lane == 0) {
#pragma unroll
        for (int j = 0; j < 9; j++) sc[wid][j] = cnt[j];
    }
    __syncthreads();
    if (threadIdx.x < 9) {
        int tot = sc[0][threadIdx.x] + sc[1][threadIdx.x] + sc[2][threadIdx.x] + sc[3][threadIdx.x];
        atomicAdd(&counts[(n * SQE + s) * 9 + threadIdx.x], tot);
    }
}

// Pass 3: type_list (from counts) -> wsum = sum_s region_soft*tl, + wsum min/max.
// Rows with all-zero type_list contribute exactly +0.0 -> skipped (bitwise identity).
__global__ __launch_bounds__(256) void k_wsum(const float* __restrict__ pred,
                                              unsigned* mm, const int* __restrict__ counts,
                                              float* __restrict__ wsum) {
    __shared__ float tl[SQE][3];
    int tid = threadIdx.x;
    int n = blockIdx.x >> 6;   // 64 blocks per batch element
    if (tid < SQE * 3) {
        int s = tid / 3, ch = tid - 3 * (tid / 3);
        const int* cc = counts + (n * SQE + s) * 9 + ch * 3;
        int c0 = cc[0], c1 = cc[1], c2 = cc[2];
        tl[s][ch] = (c2 > c1 && c2 > c0) ? 1.0f : ((c1 > c0) ? 0.5f : 0.0f);
    }
    __syncthreads();
    if (tid < SQE) {
        int code = (int)(tl[tid][0] * 2.0f) * 9 + (int)(tl[tid][1] * 2.0f) * 3 + (int)(tl[tid][2] * 2.0f);
        if (!((0x0559E101u >> code) & 1u)) { tl[tid][0] = 0.f; tl[tid][1] = 0.f; tl[tid][2] = 0.f; }
    }
    __syncthreads();

    float mn = fdec(~mm[0]);
    float d  = fdec(mm[1]) - mn;
    int idx = blockIdx.x * 256 + tid;
    int hw = idx & (HWPX - 1);
    const float* pr = pred + (size_t)n * S_N + 4 * (size_t)S_A + hw; // attr 4
    float a0 = 0.f, a1 = 0.f, a2 = 0.f;
    for (int s = 0; s < SQE; s++) {
        float t0 = tl[s][0], t1 = tl[s][1], t2 = tl[s][2];
        if (t0 + t1 + t2 != 0.0f) {
            const float* ps = pr + (size_t)s * S_S;
            float g0 = (ps[0] - mn) / d;
            float g1 = (ps[S_C] - mn) / d;
            float g2 = (ps[2 * S_C] - mn) / d;
            float r = sigm((g0 - 0.9f) * 10.0f) * sigm((g1 - 0.9f) * 10.0f) * sigm((g2 - 0.9f) * 10.0f);
            a0 += r * t0;
            a1 += r * t1;
            a2 += r * t2;
        }
    }
    wsum[(n * 3 + 0) * HWPX + hw] = a0;
    wsum[(n * 3 + 1) * HWPX + hw] = a1;
    wsum[(n * 3 + 2) * HWPX + hw] = a2;

    float mnl = fminf(a0, fminf(a1, a2));
    float mxl = fmaxf(a0, fmaxf(a1, a2));
    blk_minmax_atomic(mnl, mxl, mm, 2);
}

// Pass 4: squared-error partials + last-block-done final reduce -> out[0]
__global__ __launch_bounds__(512) void k_loss(const float* __restrict__ gt,
                                              const unsigned* __restrict__ mm,
                                              const float* __restrict__ slaw,
                                              const float* __restrict__ wsum,
                                              float* __restrict__ part,
                                              unsigned* __restrict__ ctr,
                                              float* __restrict__ out) {
    float mn  = fdec(~mm[0]);
    float d   = fdec(mm[1]) - mn;
    float mn2 = fdec(~mm[2]);
    float d2  = fdec(mm[3]) - mn2;
    int idx = blockIdx.x * 512 + threadIdx.x;  // 768 blocks * 512 = NOUT
    int hw = idx & (HWPX - 1);
    int nc = idx >> 14;
    int n = nc / 3, c = nc - 3 * (nc / 3);
    float gtn = (gt[((size_t)(n * 4 + c)) * HWPX + hw] + 1.0f) * 0.5f;
    float law = (slaw[idx] - 42.0f * mn) / d;          // affine-equivalent of sum of normalized
    float rc  = (wsum[idx] - mn2) / d2;
    float comp = fminf(fmaxf(rc + law, 0.0f), 1.0f);
    float diff = comp - gtn;
    float se = diff * diff;

    __shared__ float sdata[512];
    sdata[threadIdx.x] = se;
    __syncthreads();
#pragma unroll
    for (int s = 256; s > 0; s >>= 1) {
        if (threadIdx.x < s) sdata[threadIdx.x] += sdata[threadIdx.x + s];
        __syncthreads();
    }
    __shared__ int isLast;
    if (threadIdx.x == 0) {
        part[blockIdx.x] = sdata[0];
        __threadfence();
        unsigned prev = atomicAdd(ctr, 1u);
        isLast = (prev == 767u) ? 1 : 0;
        if (isLast) __threadfence();
    }
    __syncthreads();
    if (isLast) {
        float v = part[threadIdx.x] + ((threadIdx.x < 256) ? part[threadIdx.x + 512] : 0.0f);
        sdata[threadIdx.x] = v;
        __syncthreads();
#pragma unroll
        for (int s = 256; s > 0; s >>= 1) {
            if (threadIdx.x < s) sdata[threadIdx.x] += sdata[threadIdx.x + s];
            __syncthreads();
        }
        if (threadIdx.x == 0) out[0] = sdata[0] / (float)NOUT;  // * IMG_WEIGHT (1.0)
    }
}

extern "C" void kernel_launch(void* const* d_in, const int* in_sizes, int n_in,
                              void* d_out, int out_size, void* d_ws, size_t ws_size,
                              hipStream_t stream) {
    const float* GT   = (const float*)d_in[0];
    const float* Pred = (const float*)d_in[1];
    float* out = (float*)d_out;
    char* ws = (char*)d_ws;
    unsigned* mm   = (unsigned*)(ws + WS_MM);
    unsigned* ctr  = (unsigned*)(ws + WS_CTR);
    int* counts    = (int*)(ws + WS_COUNTS);
    float* slaw    = (float*)(ws + WS_LAW);
    float* wsum    = (float*)(ws + WS_WSUM);
    float* part    = (float*)(ws + WS_PART);

    hipMemsetAsync(ws, 0, 4096, stream);                       // mm, ctr, counts
    k_p1<<<384 + NB * 210, 256, 0, stream>>>(Pred, mm, (float4*)slaw);
    k_counts<<<896, 256, 0, stream>>>(Pred, mm, counts);
    k_wsum<<<NB * HWPX / 256, 256, 0, stream>>>(Pred, mm, counts, wsum);
    k_loss<<<NOUT / 512, 512, 0, stream>>>(GT, mm, slaw, wsum, part, ctr, out);
}

// Round 4
// 297.000 us; speedup vs baseline: 1.0736x; 1.0449x over previous
//
#include <hip/hip_runtime.h>
#include <math.h>

#define ATTRI 6
#define SQE   14
#define HWPX  16384            // 128*128
#define NB    8
#define S_C   HWPX             // channel stride in Pred (floats)
#define S_S   (4 * HWPX)       // sqe stride
#define S_A   (SQE * 4 * HWPX) // attr stride = 917504
#define S_N   (ATTRI * SQE * 4 * HWPX) // batch stride = 5505024
#define NPRED (NB * S_N)       // 44040192
#define NOUT  (NB * 3 * HWPX)  // 393216 composite elements

// ws layout (bytes); first 4096 bytes zeroed by hipMemsetAsync each call
#define WS_MM     0                      // 4 uints: ~minKey, maxKey, ~minKey2, maxKey2 (atomicMax, init 0)
#define WS_CTR    16                     // 1 uint: last-block counter
#define WS_COUNTS 32                     // int[8*14*9] = 1008 ints (ends at 4064)
#define WS_LAW    4096                   // float[NOUT] raw sums
#define WS_WSUM   (4096 + NOUT * 4)      // float[NOUT]
#define WS_PART   (WS_WSUM + NOUT * 4)   // float[768]

// monotone float<->uint key (unsigned compare == float compare); inputs here are never NaN
__device__ __forceinline__ unsigned fkey(float f) {
    unsigned u = __float_as_uint(f);
    return (u & 0x80000000u) ? ~u : (u | 0x80000000u);
}
__device__ __forceinline__ float fdec(unsigned k) {
    unsigned u = (k & 0x80000000u) ? (k & 0x7FFFFFFFu) : ~k;
    return __uint_as_float(u);
}
__device__ __forceinline__ float sigm(float x) { return 1.0f / (1.0f + expf(-x)); }

__device__ __forceinline__ void blk_minmax_atomic(float mnl, float mxl, unsigned* mm, int mmOff) {
#pragma unroll
    for (int o = 32; o; o >>= 1) {
        mnl = fminf(mnl, __shfl_down(mnl, o));
        mxl = fmaxf(mxl, __shfl_down(mxl, o));
    }
    __shared__ float smn[4], smx[4];
    int wid = threadIdx.x >> 6, lane = threadIdx.x & 63;
    if (lane == 0) { smn[wid] = mnl; smx[wid] = mxl; }
    __syncthreads();
    if (threadIdx.x == 0) {
        float bmn = fminf(fminf(smn[0], smn[1]), fminf(smn[2], smn[3]));
        float bmx = fmaxf(fmaxf(smx[0], smx[1]), fmaxf(smx[2], smx[3]));
        atomicMax(&mm[mmOff + 0], ~fkey(bmn));   // min tracked as max of complemented key
        atomicMax(&mm[mmOff + 1], fkey(bmx));
    }
}

// Pass 1: single full read of Pred (176 MB): global min/max + raw LAW sums.
// Balanced: EVERY thread does exactly 42 float4 loads (1024 blocks x 256 thr x 42 x 16B = 176 MB).
//   Blocks [0,384): the 42 used planes of attrs {2,3,5} ch0..2 -> law sum + minmax (42 loads).
//   Blocks [384,1024): remaining 210 planes/batch via flat rid sweep (42 loads, lane-contiguous).
__global__ __launch_bounds__(256) void k_p1(const float* __restrict__ pred, unsigned* mm,
                                            float4* __restrict__ slaw) {
    float mnl = INFINITY, mxl = -INFINITY;
    int b = blockIdx.x, t = threadIdx.x;
    if (b < 384) {
        int idx = b * 256 + t;               // float4 index into [n][c][hw/4]
        int hw4 = idx & 4095;
        int nc = idx >> 12;                  // 0..23
        int n = nc / 3, c = nc - 3 * (nc / 3);
        const float4* p = (const float4*)(pred + (size_t)n * S_N + (size_t)c * S_C) + hw4;
        float4 s = make_float4(0.f, 0.f, 0.f, 0.f);
        const int attrs[3] = {2, 3, 5};
#pragma unroll
        for (int ai = 0; ai < 3; ai++) {
            const float4* pa = p + (size_t)attrs[ai] * (S_A / 4);
#pragma unroll
            for (int ss = 0; ss < SQE; ss++) {
                float4 v = pa[(size_t)ss * (S_S / 4)];
                s.x += v.x; s.y += v.y; s.z += v.z; s.w += v.w;
                mnl = fminf(mnl, fminf(fminf(v.x, v.y), fminf(v.z, v.w)));
                mxl = fmaxf(mxl, fmaxf(fmaxf(v.x, v.y), fmaxf(v.z, v.w)));
            }
        }
        slaw[idx] = s;
    } else {
        int rid = (b - 384) * 256 + t;       // [0, 163840); 163840*42 = 6881280 float4s
        const float4* p4 = (const float4*)pred;
#pragma unroll 6
        for (int k = 0; k < 42; k++) {
            int r = k * 163840 + rid;
            int n = r / 860160;              // 210 planes * 4096 f4
            int rem = r - n * 860160;
            int pi = rem >> 12;              // 0..209
            int off = rem & 4095;
            int plane;                       // plane = a*56 + s*4 + c; the 210 not in law section
            if (pi < 112)      plane = pi;                      // attrs 0,1 (all planes)
            else if (pi < 126) plane = 115 + ((pi - 112) << 2); // attr 2 ch3
            else if (pi < 140) plane = 171 + ((pi - 126) << 2); // attr 3 ch3
            else if (pi < 196) plane = 84 + pi;                 // attr 4 all (224 + pi-140)
            else               plane = 283 + ((pi - 196) << 2); // attr 5 ch3
            float4 v = p4[(size_t)n * (S_N / 4) + (size_t)plane * 4096 + off];
            mnl = fminf(mnl, fminf(fminf(v.x, v.y), fminf(v.z, v.w)));
            mxl = fmaxf(mxl, fmaxf(fmaxf(v.x, v.y), fmaxf(v.z, v.w)));
        }
    }
    blk_minmax_atomic(mnl, mxl, mm, 0);
}

// Pass 2: color-threshold counts on attr 0 (bit-exact (x-mn)/d predicates), float4 loads.
__global__ __launch_bounds__(256) void k_counts(const float* __restrict__ pred,
                                                const unsigned* __restrict__ mm,
                                                int* __restrict__ counts) {
    float mn = fdec(~mm[0]);
    float d  = fdec(mm[1]) - mn;
    int b = blockIdx.x;                   // 896 blocks
    int pair = b >> 3, slice = b & 7;
    int n = pair / SQE, s = pair - SQE * (pair / SQE);
    const float4* base = (const float4*)(pred + (size_t)n * S_N + (size_t)s * S_S);
    int cnt[9];
#pragma unroll
    for (int j = 0; j < 9; j++) cnt[j] = 0;
#pragma unroll
    for (int k = 0; k < 2; k++) {
        int p = slice * 512 + k * 256 + threadIdx.x;    // float4 index within plane
        float4 va = base[3 * 4096 + p];
        float4 v0 = base[p];
        float4 v1 = base[4096 + p];
        float4 v2 = base[2 * 4096 + p];
        const float ax[4] = {va.x, va.y, va.z, va.w};
        const float cx[3][4] = {{v0.x, v0.y, v0.z, v0.w},
                                {v1.x, v1.y, v1.z, v1.w},
                                {v2.x, v2.y, v2.z, v2.w}};
#pragma unroll
        for (int e = 0; e < 4; e++) {
            float a = (ax[e] - mn) / d;
            bool av = a > 0.8f;
#pragma unroll
            for (int ch = 0; ch < 3; ch++) {
                float g = (cx[ch][e] - mn) / d;
                cnt[ch * 3 + 0] += (g > 0.0f && g < 0.2f && av) ? 1 : 0;
                cnt[ch * 3 + 1] += (g > 0.4f && g < 0.6f) ? 1 : 0;
                cnt[ch * 3 + 2] += (g > 0.8f) ? 1 : 0;
            }
        }
    }
#pragma unroll
    for (int o = 32; o; o >>= 1) {
#pragma unroll
        for (int j = 0; j < 9; j++) cnt[j] += __shfl_down(cnt[j], o);
    }
    __shared__ int sc[4][9];
    int wid = threadIdx.x >> 6, lane = threadIdx.x & 63;
    if (lane == 0) {
#pragma unroll
        for (int j = 0; j < 9; j++) sc[wid][j] = cnt[j];
    }
    __syncthreads();
    if (threadIdx.x < 9) {
        int tot = sc[0][threadIdx.x] + sc[1][threadIdx.x] + sc[2][threadIdx.x] + sc[3][threadIdx.x];
        atomicAdd(&counts[(n * SQE + s) * 9 + threadIdx.x], tot);
    }
}

// Pass 3: type_list (from counts) -> wsum = sum_s region_soft*tl, + wsum min/max.
// Rows with all-zero type_list contribute exactly +0.0 -> skipped (bitwise identity).
__global__ __launch_bounds__(256) void k_wsum(const float* __restrict__ pred,
                                              unsigned* mm, const int* __restrict__ counts,
                                              float* __restrict__ wsum) {
    __shared__ float tl[SQE][3];
    int tid = threadIdx.x;
    int n = blockIdx.x >> 6;   // 64 blocks per batch element
    if (tid < SQE * 3) {
        int s = tid / 3, ch = tid - 3 * (tid / 3);
        const int* cc = counts + (n * SQE + s) * 9 + ch * 3;
        int c0 = cc[0], c1 = cc[1], c2 = cc[2];
        tl[s][ch] = (c2 > c1 && c2 > c0) ? 1.0f : ((c1 > c0) ? 0.5f : 0.0f);
    }
    __syncthreads();
    if (tid < SQE) {
        int code = (int)(tl[tid][0] * 2.0f) * 9 + (int)(tl[tid][1] * 2.0f) * 3 + (int)(tl[tid][2] * 2.0f);
        if (!((0x0559E101u >> code) & 1u)) { tl[tid][0] = 0.f; tl[tid][1] = 0.f; tl[tid][2] = 0.f; }
    }
    __syncthreads();

    float mn = fdec(~mm[0]);
    float d  = fdec(mm[1]) - mn;
    int idx = blockIdx.x * 256 + tid;
    int hw = idx & (HWPX - 1);
    const float* pr = pred + (size_t)n * S_N + 4 * (size_t)S_A + hw; // attr 4
    float a0 = 0.f, a1 = 0.f, a2 = 0.f;
    for (int s = 0; s < SQE; s++) {
        float t0 = tl[s][0], t1 = tl[s][1], t2 = tl[s][2];
        if (t0 + t1 + t2 != 0.0f) {
            const float* ps = pr + (size_t)s * S_S;
            float g0 = (ps[0] - mn) / d;
            float g1 = (ps[S_C] - mn) / d;
            float g2 = (ps[2 * S_C] - mn) / d;
            float r = sigm((g0 - 0.9f) * 10.0f) * sigm((g1 - 0.9f) * 10.0f) * sigm((g2 - 0.9f) * 10.0f);
            a0 += r * t0;
            a1 += r * t1;
            a2 += r * t2;
        }
    }
    wsum[(n * 3 + 0) * HWPX + hw] = a0;
    wsum[(n * 3 + 1) * HWPX + hw] = a1;
    wsum[(n * 3 + 2) * HWPX + hw] = a2;

    float mnl = fminf(a0, fminf(a1, a2));
    float mxl = fmaxf(a0, fmaxf(a1, a2));
    blk_minmax_atomic(mnl, mxl, mm, 2);
}

// Pass 4: squared-error partials + last-block-done final reduce -> out[0]
__global__ __launch_bounds__(512) void k_loss(const float* __restrict__ gt,
                                              const unsigned* __restrict__ mm,
                                              const float* __restrict__ slaw,
                                              const float* __restrict__ wsum,
                                              float* __restrict__ part,
                                              unsigned* __restrict__ ctr,
                                              float* __restrict__ out) {
    float mn  = fdec(~mm[0]);
    float d   = fdec(mm[1]) - mn;
    float mn2 = fdec(~mm[2]);
    float d2  = fdec(mm[3]) - mn2;
    int idx = blockIdx.x * 512 + threadIdx.x;  // 768 blocks * 512 = NOUT
    int hw = idx & (HWPX - 1);
    int nc = idx >> 14;
    int n = nc / 3, c = nc - 3 * (nc / 3);
    float gtn = (gt[((size_t)(n * 4 + c)) * HWPX + hw] + 1.0f) * 0.5f;
    float law = (slaw[idx] - 42.0f * mn) / d;          // affine-equivalent of sum of normalized
    float rc  = (wsum[idx] - mn2) / d2;
    float comp = fminf(fmaxf(rc + law, 0.0f), 1.0f);
    float diff = comp - gtn;
    float se = diff * diff;

    __shared__ float sdata[512];
    sdata[threadIdx.x] = se;
    __syncthreads();
#pragma unroll
    for (int s = 256; s > 0; s >>= 1) {
        if (threadIdx.x < s) sdata[threadIdx.x] += sdata[threadIdx.x + s];
        __syncthreads();
    }
    __shared__ int isLast;
    if (threadIdx.x == 0) {
        part[blockIdx.x] = sdata[0];
        __threadfence();
        unsigned prev = atomicAdd(ctr, 1u);
        isLast = (prev == 767u) ? 1 : 0;
        if (isLast) __threadfence();
    }
    __syncthreads();
    if (isLast) {
        float v = part[threadIdx.x] + ((threadIdx.x < 256) ? part[threadIdx.x + 512] : 0.0f);
        sdata[threadIdx.x] = v;
        __syncthreads();
#pragma unroll
        for (int s = 256; s > 0; s >>= 1) {
            if (threadIdx.x < s) sdata[threadIdx.x] += sdata[threadIdx.x + s];
            __syncthreads();
        }
        if (threadIdx.x == 0) out[0] = sdata[0] / (float)NOUT;  // * IMG_WEIGHT (1.0)
    }
}

extern "C" void kernel_launch(void* const* d_in, const int* in_sizes, int n_in,
                              void* d_out, int out_size, void* d_ws, size_t ws_size,
                              hipStream_t stream) {
    const float* GT   = (const float*)d_in[0];
    const float* Pred = (const float*)d_in[1];
    float* out = (float*)d_out;
    char* ws = (char*)d_ws;
    unsigned* mm   = (unsigned*)(ws + WS_MM);
    unsigned* ctr  = (unsigned*)(ws + WS_CTR);
    int* counts    = (int*)(ws + WS_COUNTS);
    float* slaw    = (float*)(ws + WS_LAW);
    float* wsum    = (float*)(ws + WS_WSUM);
    float* part    = (float*)(ws + WS_PART);

    hipMemsetAsync(ws, 0, 4096, stream);                       // mm, ctr, counts
    k_p1<<<1024, 256, 0, stream>>>(Pred, mm, (float4*)slaw);   // balanced: 42 f4 loads/thread
    k_counts<<<896, 256, 0, stream>>>(Pred, mm, counts);
    k_wsum<<<NB * HWPX / 256, 256, 0, stream>>>(Pred, mm, counts, wsum);
    k_loss<<<NOUT / 512, 512, 0, stream>>>(GT, mm, slaw, wsum, part, ctr, out);
}

// Round 8
// 288.943 us; speedup vs baseline: 1.1035x; 1.0279x over previous
//
#include <hip/hip_runtime.h>
#include <math.h>

#define ATTRI 6
#define SQE   14
#define HWPX  16384            // 128*128
#define NB    8
#define S_C   HWPX             // channel stride in Pred (floats)
#define S_S   (4 * HWPX)       // sqe stride
#define S_A   (SQE * 4 * HWPX) // attr stride = 917504
#define S_N   (ATTRI * SQE * 4 * HWPX) // batch stride = 5505024
#define NOUT  (NB * 3 * HWPX)  // 393216 composite elements

// ws layout (bytes). NO pre-zeroing needed: every cell is plain-stored before read;
// the loss counter is zeroed by k_wsum (stream-ordered before k_loss).
#define WS_PMN   0                       // float[1024] per-block min (pass 1)
#define WS_PMX   4096                    // float[1024] per-block max
#define WS_PMN2  8192                    // float[512]  per-block wsum min
#define WS_PMX2  10240                   // float[512]  per-block wsum max
#define WS_CTR   12288                   // 1 uint (zeroed by k_wsum)
#define WS_PCNT  12352                   // int[896*9] per-(pair,slice) counts
#define WS_PART  45056                   // float[768] loss partials
#define WS_SLAW  65536                   // float[NOUT] raw law sums
#define WS_WSUM  (65536 + NOUT * 4)      // float[NOUT]

__device__ __forceinline__ float sigm(float x) { return 1.0f / (1.0f + expf(-x)); }

// block-wide min/max reduce over NW waves, result broadcast to ALL threads.
template <int NW>
__device__ __forceinline__ void bcast_minmax(float& mnl, float& mxl) {
#pragma unroll
    for (int o = 32; o; o >>= 1) {
        mnl = fminf(mnl, __shfl_down(mnl, o));
        mxl = fmaxf(mxl, __shfl_down(mxl, o));
    }
    __shared__ float smn[NW], smx[NW];
    int wid = threadIdx.x >> 6, lane = threadIdx.x & 63;
    __syncthreads();
    if (lane == 0) { smn[wid] = mnl; smx[wid] = mxl; }
    __syncthreads();
    float a = smn[0], b = smx[0];
#pragma unroll
    for (int w = 1; w < NW; w++) { a = fminf(a, smn[w]); b = fmaxf(b, smx[w]); }
    mnl = a; mxl = b;
}

// Pass 1: single full read of Pred (176 MB): per-block min/max + raw LAW sums.
// Balanced: EVERY thread does exactly 42 float4 loads (1024 blocks x 256 thr x 42 x 16B).
__global__ __launch_bounds__(256) void k_p1(const float* __restrict__ pred,
                                            float* __restrict__ pmn, float* __restrict__ pmx,
                                            float4* __restrict__ slaw) {
    float mnl = INFINITY, mxl = -INFINITY;
    int b = blockIdx.x, t = threadIdx.x;
    if (b < 384) {
        int idx = b * 256 + t;               // float4 index into [n][c][hw/4]
        int hw4 = idx & 4095;
        int nc = idx >> 12;                  // 0..23
        int n = nc / 3, c = nc - 3 * (nc / 3);
        const float4* p = (const float4*)(pred + (size_t)n * S_N + (size_t)c * S_C) + hw4;
        float4 s = make_float4(0.f, 0.f, 0.f, 0.f);
        const int attrs[3] = {2, 3, 5};
#pragma unroll
        for (int ai = 0; ai < 3; ai++) {
            const float4* pa = p + (size_t)attrs[ai] * (S_A / 4);
#pragma unroll
            for (int ss = 0; ss < SQE; ss++) {
                float4 v = pa[(size_t)ss * (S_S / 4)];
                s.x += v.x; s.y += v.y; s.z += v.z; s.w += v.w;
                mnl = fminf(mnl, fminf(fminf(v.x, v.y), fminf(v.z, v.w)));
                mxl = fmaxf(mxl, fmaxf(fmaxf(v.x, v.y), fmaxf(v.z, v.w)));
            }
        }
        slaw[idx] = s;
    } else {
        int rid = (b - 384) * 256 + t;       // [0, 163840); 163840*42 = 6881280 float4s
        const float4* p4 = (const float4*)pred;
#pragma unroll 6
        for (int k = 0; k < 42; k++) {
            int r = k * 163840 + rid;
            int n = r / 860160;              // 210 planes * 4096 f4
            int rem = r - n * 860160;
            int pi = rem >> 12;              // 0..209
            int off = rem & 4095;
            int plane;                       // plane = a*56 + s*4 + c; the 210 non-law planes
            if (pi < 112)      plane = pi;                      // attrs 0,1 (all)
            else if (pi < 126) plane = 115 + ((pi - 112) << 2); // attr 2 ch3
            else if (pi < 140) plane = 171 + ((pi - 126) << 2); // attr 3 ch3
            else if (pi < 196) plane = 84 + pi;                 // attr 4 all
            else               plane = 283 + ((pi - 196) << 2); // attr 5 ch3
            float4 v = p4[(size_t)n * (S_N / 4) + (size_t)plane * 4096 + off];
            mnl = fminf(mnl, fminf(fminf(v.x, v.y), fminf(v.z, v.w)));
            mxl = fmaxf(mxl, fmaxf(fmaxf(v.x, v.y), fmaxf(v.z, v.w)));
        }
    }
    bcast_minmax<4>(mnl, mxl);
    if (t == 0) { pmn[b] = mnl; pmx[b] = mxl; }
}

// reduce the 1024-entry per-block min/max arrays (256 threads, float4 each), broadcast
__device__ __forceinline__ void global_minmax_256(const float* pmn, const float* pmx,
                                                  float& mn_g, float& d_g) {
    float4 a = ((const float4*)pmn)[threadIdx.x];
    float4 c = ((const float4*)pmx)[threadIdx.x];
    float mnl = fminf(fminf(a.x, a.y), fminf(a.z, a.w));
    float mxl = fmaxf(fmaxf(c.x, c.y), fmaxf(c.z, c.w));
    bcast_minmax<4>(mnl, mxl);
    mn_g = mnl; d_g = mxl - mnl;
}

// Pass 2: color-threshold counts on attr 0 (bit-exact (x-mn)/d predicates), plain stores.
__global__ __launch_bounds__(256) void k_counts(const float* __restrict__ pred,
                                                const float* __restrict__ pmn,
                                                const float* __restrict__ pmx,
                                                int* __restrict__ pcnt) {
    float mn, d;
    global_minmax_256(pmn, pmx, mn, d);
    int b = blockIdx.x;                   // 896 blocks
    int pair = b >> 3, slice = b & 7;
    int n = pair / SQE, s = pair - SQE * (pair / SQE);
    const float4* base = (const float4*)(pred + (size_t)n * S_N + (size_t)s * S_S);
    int cnt[9];
#pragma unroll
    for (int j = 0; j < 9; j++) cnt[j] = 0;
#pragma unroll
    for (int k = 0; k < 2; k++) {
        int p = slice * 512 + k * 256 + threadIdx.x;    // float4 index within plane
        float4 va = base[3 * 4096 + p];
        float4 v0 = base[p];
        float4 v1 = base[4096 + p];
        float4 v2 = base[2 * 4096 + p];
        const float ax[4] = {va.x, va.y, va.z, va.w};
        const float cx[3][4] = {{v0.x, v0.y, v0.z, v0.w},
                                {v1.x, v1.y, v1.z, v1.w},
                                {v2.x, v2.y, v2.z, v2.w}};
#pragma unroll
        for (int e = 0; e < 4; e++) {
            float a = (ax[e] - mn) / d;
            bool av = a > 0.8f;
#pragma unroll
            for (int ch = 0; ch < 3; ch++) {
                float g = (cx[ch][e] - mn) / d;
                cnt[ch * 3 + 0] += (g > 0.0f && g < 0.2f && av) ? 1 : 0;
                cnt[ch * 3 + 1] += (g > 0.4f && g < 0.6f) ? 1 : 0;
                cnt[ch * 3 + 2] += (g > 0.8f) ? 1 : 0;
            }
        }
    }
#pragma unroll
    for (int o = 32; o; o >>= 1) {
#pragma unroll
        for (int j = 0; j < 9; j++) cnt[j] += __shfl_down(cnt[j], o);
    }
    __shared__ int sc[4][9];
    int wid = threadIdx.x >> 6, lane = threadIdx.x & 63;
    if (lane == 0) {
#pragma unroll
        for (int j = 0; j < 9; j++) sc[wid][j] = cnt[j];
    }
    __syncthreads();
    if (threadIdx.x < 9)
        pcnt[b * 9 + threadIdx.x] = sc[0][threadIdx.x] + sc[1][threadIdx.x]
                                  + sc[2][threadIdx.x] + sc[3][threadIdx.x];
}

// Pass 3: type_list (from per-slice counts) -> wsum + per-block wsum min/max. Zeroes ctr.
__global__ __launch_bounds__(256) void k_wsum(const float* __restrict__ pred,
                                              const float* __restrict__ pmn,
                                              const float* __restrict__ pmx,
                                              const int* __restrict__ pcnt,
                                              float* __restrict__ wsum,
                                              float* __restrict__ pmn2,
                                              float* __restrict__ pmx2,
                                              unsigned* __restrict__ ctr) {
    float mn, d;
    global_minmax_256(pmn, pmx, mn, d);
    int tid = threadIdx.x, b = blockIdx.x;
    if (b == 0 && tid == 0) ctr[0] = 0;        // init for k_loss (stream-ordered)
    __shared__ float tl[SQE][3];
    int n = b >> 6;   // 64 blocks per batch element
    if (tid < SQE * 3) {
        int s = tid / 3, ch = tid - 3 * (tid / 3);
        const int* pc = pcnt + ((n * SQE + s) * 8) * 9 + ch * 3;
        int c0 = 0, c1 = 0, c2 = 0;
#pragma unroll
        for (int sl = 0; sl < 8; sl++) { c0 += pc[sl * 9]; c1 += pc[sl * 9 + 1]; c2 += pc[sl * 9 + 2]; }
        tl[s][ch] = (c2 > c1 && c2 > c0) ? 1.0f : ((c1 > c0) ? 0.5f : 0.0f);
    }
    __syncthreads();
    if (tid < SQE) {
        int code = (int)(tl[tid][0] * 2.0f) * 9 + (int)(tl[tid][1] * 2.0f) * 3 + (int)(tl[tid][2] * 2.0f);
        if (!((0x0559E101u >> code) & 1u)) { tl[tid][0] = 0.f; tl[tid][1] = 0.f; tl[tid][2] = 0.f; }
    }
    __syncthreads();

    int idx = b * 256 + tid;
    int hw = idx & (HWPX - 1);
    const float* pr = pred + (size_t)n * S_N + 4 * (size_t)S_A + hw; // attr 4
    float a0 = 0.f, a1 = 0.f, a2 = 0.f;
    for (int s = 0; s < SQE; s++) {
        float t0 = tl[s][0], t1 = tl[s][1], t2 = tl[s][2];
        if (t0 + t1 + t2 != 0.0f) {            // skipped rows contribute exactly +0.0
            const float* ps = pr + (size_t)s * S_S;
            float g0 = (ps[0] - mn) / d;
            float g1 = (ps[S_C] - mn) / d;
            float g2 = (ps[2 * S_C] - mn) / d;
            float r = sigm((g0 - 0.9f) * 10.0f) * sigm((g1 - 0.9f) * 10.0f) * sigm((g2 - 0.9f) * 10.0f);
            a0 += r * t0; a1 += r * t1; a2 += r * t2;
        }
    }
    wsum[(n * 3 + 0) * HWPX + hw] = a0;
    wsum[(n * 3 + 1) * HWPX + hw] = a1;
    wsum[(n * 3 + 2) * HWPX + hw] = a2;

    float mnl = fminf(a0, fminf(a1, a2));
    float mxl = fmaxf(a0, fmaxf(a1, a2));
    bcast_minmax<4>(mnl, mxl);
    if (tid == 0) { pmn2[b] = mnl; pmx2[b] = mxl; }
}

// Pass 4: squared-error partials + last-block-done final reduce -> out[0]
__global__ __launch_bounds__(512) void k_loss(const float* __restrict__ gt,
                                              const float* __restrict__ pmn,
                                              const float* __restrict__ pmx,
                                              const float* __restrict__ pmn2,
                                              const float* __restrict__ pmx2,
                                              const float* __restrict__ slaw,
                                              const float* __restrict__ wsum,
                                              float* __restrict__ part,
                                              unsigned* __restrict__ ctr,
                                              float* __restrict__ out) {
    int t = threadIdx.x;
    float mn, d;
    {   // 1024 entries: each of 512 threads covers 2
        float mnl = fminf(pmn[t], pmn[t + 512]);
        float mxl = fmaxf(pmx[t], pmx[t + 512]);
        bcast_minmax<8>(mnl, mxl);
        mn = mnl; d = mxl - mnl;
    }
    float mn2, d2;
    {   // 512 entries
        float mnl = pmn2[t], mxl = pmx2[t];
        bcast_minmax<8>(mnl, mxl);
        mn2 = mnl; d2 = mxl - mnl;
    }
    int idx = blockIdx.x * 512 + t;            // 768 blocks * 512 = NOUT
    int hw = idx & (HWPX - 1);
    int nc = idx >> 14;
    int n = nc / 3, c = nc - 3 * (nc / 3);
    float gtn = (gt[((size_t)(n * 4 + c)) * HWPX + hw] + 1.0f) * 0.5f;
    float law = (slaw[idx] - 42.0f * mn) / d;  // affine-equivalent of sum of normalized
    float rc  = (wsum[idx] - mn2) / d2;
    float comp = fminf(fmaxf(rc + law, 0.0f), 1.0f);
    float diff = comp - gtn;

    __shared__ float sdata[512];
    sdata[t] = diff * diff;
    __syncthreads();
#pragma unroll
    for (int s = 256; s > 0; s >>= 1) {
        if (t < s) sdata[t] += sdata[t + s];
        __syncthreads();
    }
    __shared__ int isLast;
    if (t == 0) {
        part[blockIdx.x] = sdata[0];
        __threadfence();
        unsigned prev = atomicAdd(ctr, 1u);
        isLast = (prev == 767u) ? 1 : 0;
        if (isLast) __threadfence();
    }
    __syncthreads();
    if (isLast) {
        float v = part[t] + ((t < 256) ? part[t + 512] : 0.0f);
        sdata[t] = v;
        __syncthreads();
#pragma unroll
        for (int s = 256; s > 0; s >>= 1) {
            if (t < s) sdata[t] += sdata[t + s];
            __syncthreads();
        }
        if (t == 0) out[0] = sdata[0] / (float)NOUT;  // * IMG_WEIGHT (1.0)
    }
}

extern "C" void kernel_launch(void* const* d_in, const int* in_sizes, int n_in,
                              void* d_out, int out_size, void* d_ws, size_t ws_size,
                              hipStream_t stream) {
    const float* GT   = (const float*)d_in[0];
    const float* Pred = (const float*)d_in[1];
    float* out = (float*)d_out;
    char* ws = (char*)d_ws;
    float* pmn  = (float*)(ws + WS_PMN);
    float* pmx  = (float*)(ws + WS_PMX);
    float* pmn2 = (float*)(ws + WS_PMN2);
    float* pmx2 = (float*)(ws + WS_PMX2);
    unsigned* ctr = (unsigned*)(ws + WS_CTR);
    int*   pcnt = (int*)  (ws + WS_PCNT);
    float* part = (float*)(ws + WS_PART);
    float* slaw = (float*)(ws + WS_SLAW);
    float* wsm  = (float*)(ws + WS_WSUM);

    k_p1<<<1024, 256, 0, stream>>>(Pred, pmn, pmx, (float4*)slaw);
    k_counts<<<896, 256, 0, stream>>>(Pred, pmn, pmx, pcnt);
    k_wsum<<<NB * HWPX / 256, 256, 0, stream>>>(Pred, pmn, pmx, pcnt, wsm, pmn2, pmx2, ctr);
    k_loss<<<NOUT / 512, 512, 0, stream>>>(GT, pmn, pmx, pmn2, pmx2, slaw, wsm, part, ctr, out);
}